// Round 5
// baseline (571.692 us; speedup 1.0000x reference)
//
#include <hip/hip_runtime.h>
#include <hip/hip_cooperative_groups.h>

namespace cg = cooperative_groups;

#define NB 4
#define NC 16
#define NP 76800
#define NK 100
#define NITER 10
#define BW2 0.0256f
#define TPB 256
#define PT 5
#define BPB 64               // blocks per batch
#define SPB 1200             // points per block stripe (64*1200 = 76800)

// ws layout (floats): means2[2][NB*NK*NC] | gnum3[3][NB*NK*NC] | gden3[3][NB*NK]
#define MEANS_OFF 0
#define GNUM_OFF  (2*NB*NK*NC)
#define GDEN_OFF  (GNUM_OFF + 3*NB*NK*NC)

__global__ void ms_init(const float* __restrict__ feat, const int* __restrict__ seed,
                        float* __restrict__ ws) {
    int t = blockIdx.x * blockDim.x + threadIdx.x;
    int stride = gridDim.x * blockDim.x;
    for (int i = t; i < 3 * NB * NK * NC + 3 * NB * NK; i += stride)
        ws[GNUM_OFF + i] = 0.f;
    if (t < NB * NK) {
        int b = t / NK;
        int idx = seed[t];
        float* m = ws + MEANS_OFF + NB * NK * NC + t * NC;  // means buffer 1 = means_{-1}
        for (int c = 0; c < NC; ++c)
            m[c] = feat[((size_t)b * NC + c) * NP + idx];
    }
}

__global__ __launch_bounds__(TPB) void ms_fused(const float* __restrict__ feat,
                                                float* __restrict__ ws,
                                                float* __restrict__ out) {
    cg::grid_group grid = cg::this_grid();
    __shared__ float sm[NK][NC];
    __shared__ float sm2[NK];
    __shared__ float snum[NK][NC];
    __shared__ float sden[NK];
    const int b = blockIdx.x / BPB;
    const int tile = blockIdx.x % BPB;
    const int tid = threadIdx.x;

    // ---- load PT point-chunks into registers ONCE (kept across all iterations) ----
    float f[PT][NC];
    float f2[PT];
    #pragma unroll
    for (int j = 0; j < PT; ++j) {
        const int lo = j * TPB + tid;              // offset within stripe
        const bool v = lo < SPB;
        const int lp = tile * SPB + (v ? lo : 0);  // clamped (avoid OOB)
        #pragma unroll
        for (int c = 0; c < NC; ++c) {
            float x = feat[((size_t)b * NC + c) * NP + lp];
            f[j][c] = v ? x : 1.0e18f;             // sentinel: d2 huge, never hits
        }
        float s = 0.f;
        #pragma unroll
        for (int c = 0; c < NC; ++c) s += f[j][c] * f[j][c];
        f2[j] = s;
    }

    // ---- 10 mean-shift iterations, one grid.sync each ----
    for (int it = 0; it < NITER; ++it) {
        const int rIdx = (it + 2) % 3, aIdx = it % 3, zIdx = (it + 1) % 3;
        const int prevM = (it + 1) & 1, curM = it & 1;
        float* gnumR = ws + GNUM_OFF + (size_t)rIdx * NB * NK * NC + (size_t)b * NK * NC;
        float* gnumA = ws + GNUM_OFF + (size_t)aIdx * NB * NK * NC + (size_t)b * NK * NC;
        float* gnumZ = ws + GNUM_OFF + (size_t)zIdx * NB * NK * NC + (size_t)b * NK * NC;
        float* gdenR = ws + GDEN_OFF + rIdx * NB * NK + b * NK;
        float* gdenA = ws + GDEN_OFF + aIdx * NB * NK + b * NK;
        float* gdenZ = ws + GDEN_OFF + zIdx * NB * NK + b * NK;
        float* mPrev = ws + MEANS_OFF + (size_t)prevM * NB * NK * NC + (size_t)b * NK * NC;
        float* mCur  = ws + MEANS_OFF + (size_t)curM  * NB * NK * NC + (size_t)b * NK * NC;

        // zero block-local accumulators
        for (int i = tid; i < NK * NC; i += TPB) (&snum[0][0])[i] = 0.f;
        if (tid < NK) sden[tid] = 0.f;

        // prologue: compute means_it from gnum/gden (exact same math as before)
        if (tid < NK) {
            const int k = tid;
            float den = gdenR[k];
            const float4* gn4 = reinterpret_cast<const float4*>(gnumR + k * NC);
            const float4* mp4 = reinterpret_cast<const float4*>(mPrev + k * NC);
            float4 g0 = gn4[0], g1 = gn4[1], g2 = gn4[2], g3 = gn4[3];
            float4 o0 = mp4[0], o1 = mp4[1], o2 = mp4[2], o3 = mp4[3];
            float gg[NC] = {g0.x,g0.y,g0.z,g0.w, g1.x,g1.y,g1.z,g1.w,
                            g2.x,g2.y,g2.z,g2.w, g3.x,g3.y,g3.z,g3.w};
            float oo[NC] = {o0.x,o0.y,o0.z,o0.w, o1.x,o1.y,o1.z,o1.w,
                            o2.x,o2.y,o2.z,o2.w, o3.x,o3.y,o3.z,o3.w};
            float inv = fmaxf(den, 1.f);
            bool pos = den > 0.f;
            float nm[NC];
            #pragma unroll
            for (int c = 0; c < NC; ++c) nm[c] = pos ? (gg[c] / inv) : oo[c];
            #pragma unroll
            for (int c = 0; c < NC; ++c) sm[k][c] = nm[c];
            float s = 0.f;
            #pragma unroll
            for (int c = 0; c < NC; ++c) s += nm[c] * nm[c];
            sm2[k] = s;
            if (tile == 0) {  // persist means_it for next iteration's prologue
                float4* mc4 = reinterpret_cast<float4*>(mCur + k * NC);
                mc4[0] = make_float4(nm[0], nm[1], nm[2], nm[3]);
                mc4[1] = make_float4(nm[4], nm[5], nm[6], nm[7]);
                mc4[2] = make_float4(nm[8], nm[9], nm[10], nm[11]);
                mc4[3] = make_float4(nm[12], nm[13], nm[14], nm[15]);
            }
        }
        // zero next iteration's global accumulation buffer (disjoint from R and A)
        if (tile == 0) {
            for (int i = tid; i < NK * NC; i += TPB) gnumZ[i] = 0.f;
            if (tid < NK) gdenZ[tid] = 0.f;
        }
        __syncthreads();

        // hot loop: all 100 k, means prefetched one k ahead, 5-way ILP
        const float4* smv = reinterpret_cast<const float4*>(&sm[0][0]);
        float4 c0 = smv[0], c1 = smv[1], c2 = smv[2], c3 = smv[3];
        float cm2 = sm2[0];
        for (int k = 0; k < NK; ++k) {
            const int kn = (k + 1 < NK) ? k + 1 : 0;
            float4 n0 = smv[kn * 4 + 0], n1 = smv[kn * 4 + 1];
            float4 n2 = smv[kn * 4 + 2], n3 = smv[kn * 4 + 3];
            float nm2 = sm2[kn];
            float mm[NC] = {c0.x,c0.y,c0.z,c0.w, c1.x,c1.y,c1.z,c1.w,
                            c2.x,c2.y,c2.z,c2.w, c3.x,c3.y,c3.z,c3.w};
            float d[PT];
            #pragma unroll
            for (int j = 0; j < PT; ++j) d[j] = 0.f;
            #pragma unroll
            for (int c = 0; c < NC; ++c) {
                float mc = mm[c];
                #pragma unroll
                for (int j = 0; j < PT; ++j) d[j] = fmaf(f[j][c], mc, d[j]);
            }
            bool h[PT];
            bool anyh = false;
            float d2v[PT];
            #pragma unroll
            for (int j = 0; j < PT; ++j) {
                d2v[j] = (f2[j] - 2.f * d[j]) + cm2;
                h[j] = d2v[j] < BW2;
                anyh |= h[j];
            }
            if (__any(anyh)) {  // rare
                #pragma unroll
                for (int j = 0; j < PT; ++j) if (h[j]) {
                    #pragma unroll
                    for (int c = 0; c < NC; ++c) atomicAdd(&snum[k][c], f[j][c]);
                    atomicAdd(&sden[k], 1.f);
                }
            }
            c0 = n0; c1 = n1; c2 = n2; c3 = n3; cm2 = nm2;
        }

        // flush block-local sums (only nonzero entries; usually none)
        __syncthreads();
        for (int i = tid; i < NK * NC; i += TPB) {
            float v = (&snum[0][0])[i];
            if (v != 0.f) atomicAdd(&gnumA[i], v);
        }
        if (tid < NK) {
            float v = sden[tid];
            if (v != 0.f) atomicAdd(&gdenA[tid], v);
        }
        grid.sync();
    }

    // ---- final means + label assignment ----
    {
        const int rIdx = (NITER + 2) % 3, prevM = (NITER + 1) & 1;
        float* gnumR = ws + GNUM_OFF + (size_t)rIdx * NB * NK * NC + (size_t)b * NK * NC;
        float* gdenR = ws + GDEN_OFF + rIdx * NB * NK + b * NK;
        float* mPrev = ws + MEANS_OFF + (size_t)prevM * NB * NK * NC + (size_t)b * NK * NC;

        if (tid < NK) {
            const int k = tid;
            float den = gdenR[k];
            const float4* gn4 = reinterpret_cast<const float4*>(gnumR + k * NC);
            const float4* mp4 = reinterpret_cast<const float4*>(mPrev + k * NC);
            float4 g0 = gn4[0], g1 = gn4[1], g2 = gn4[2], g3 = gn4[3];
            float4 o0 = mp4[0], o1 = mp4[1], o2 = mp4[2], o3 = mp4[3];
            float gg[NC] = {g0.x,g0.y,g0.z,g0.w, g1.x,g1.y,g1.z,g1.w,
                            g2.x,g2.y,g2.z,g2.w, g3.x,g3.y,g3.z,g3.w};
            float oo[NC] = {o0.x,o0.y,o0.z,o0.w, o1.x,o1.y,o1.z,o1.w,
                            o2.x,o2.y,o2.z,o2.w, o3.x,o3.y,o3.z,o3.w};
            float inv = fmaxf(den, 1.f);
            bool pos = den > 0.f;
            float nm[NC];
            #pragma unroll
            for (int c = 0; c < NC; ++c) nm[c] = pos ? (gg[c] / inv) : oo[c];
            #pragma unroll
            for (int c = 0; c < NC; ++c) sm[k][c] = nm[c];
            float s = 0.f;
            #pragma unroll
            for (int c = 0; c < NC; ++c) s += nm[c] * nm[c];
            sm2[k] = s;
            if (tile == 0) {  // final means -> output tail
                float* mo = out + (size_t)NB * NP + (size_t)b * NK * NC + k * NC;
                float4* mo4 = reinterpret_cast<float4*>(mo);
                mo4[0] = make_float4(nm[0], nm[1], nm[2], nm[3]);
                mo4[1] = make_float4(nm[4], nm[5], nm[6], nm[7]);
                mo4[2] = make_float4(nm[8], nm[9], nm[10], nm[11]);
                mo4[3] = make_float4(nm[12], nm[13], nm[14], nm[15]);
            }
        }
        __syncthreads();

        float best[PT];
        int bi[PT];
        #pragma unroll
        for (int j = 0; j < PT; ++j) { best[j] = 3.4e38f; bi[j] = 0; }

        const float4* smv = reinterpret_cast<const float4*>(&sm[0][0]);
        float4 c0 = smv[0], c1 = smv[1], c2 = smv[2], c3 = smv[3];
        float cm2 = sm2[0];
        for (int k = 0; k < NK; ++k) {
            const int kn = (k + 1 < NK) ? k + 1 : 0;
            float4 n0 = smv[kn * 4 + 0], n1 = smv[kn * 4 + 1];
            float4 n2 = smv[kn * 4 + 2], n3 = smv[kn * 4 + 3];
            float nm2 = sm2[kn];
            float mm[NC] = {c0.x,c0.y,c0.z,c0.w, c1.x,c1.y,c1.z,c1.w,
                            c2.x,c2.y,c2.z,c2.w, c3.x,c3.y,c3.z,c3.w};
            float d[PT];
            #pragma unroll
            for (int j = 0; j < PT; ++j) d[j] = 0.f;
            #pragma unroll
            for (int c = 0; c < NC; ++c) {
                float mc = mm[c];
                #pragma unroll
                for (int j = 0; j < PT; ++j) d[j] = fmaf(f[j][c], mc, d[j]);
            }
            #pragma unroll
            for (int j = 0; j < PT; ++j) {
                float d2 = (f2[j] - 2.f * d[j]) + cm2;
                if (d2 < best[j]) { best[j] = d2; bi[j] = k; }
            }
            c0 = n0; c1 = n1; c2 = n2; c3 = n3; cm2 = nm2;
        }

        #pragma unroll
        for (int j = 0; j < PT; ++j) {
            const int lo = j * TPB + tid;
            if (lo < SPB) {
                const int lp = tile * SPB + lo;
                out[(size_t)b * NP + lp] = (best[j] < BW2) ? (float)(bi[j] + 1) : 0.f;
            }
        }
    }
}

extern "C" void kernel_launch(void* const* d_in, const int* in_sizes, int n_in,
                              void* d_out, int out_size, void* d_ws, size_t ws_size,
                              hipStream_t stream) {
    const float* feat = (const float*)d_in[0];
    const int* seed = (const int*)d_in[1];
    float* out = (float*)d_out;
    float* ws = (float*)d_ws;

    ms_init<<<84, 256, 0, stream>>>(feat, seed, ws);

    void* args[] = {(void*)&feat, (void*)&ws, (void*)&out};
    hipLaunchCooperativeKernel((const void*)ms_fused, dim3(NB * BPB), dim3(TPB),
                               args, 0, stream);
}

// Round 7
// 106.378 us; speedup vs baseline: 5.3741x; 5.3741x over previous
//
#include <hip/hip_runtime.h>

#define NB 4
#define NC 16
#define NP 76800
#define NK 100
#define NITER 10
#define BW2 0.0256f
#define TPB 256
#define PT 4
#define TILEP (TPB*PT)        // 1024 points per accum block
#define NTILES (NP/TILEP)     // 75
#define KS 4                  // k-split
#define KPB (NK/KS)           // 25
// label: 1 point/thread
#define LTILEP TPB            // 256
#define LNTILES (NP/LTILEP)   // 300

// ws layout (floats): means2[2][NB*NK*NC] | gnum3[3][NB*NK*NC] | gden3[3][NB*NK]
#define MEANS_OFF 0
#define GNUM_OFF  (2*NB*NK*NC)
#define GDEN_OFF  (GNUM_OFF + 3*NB*NK*NC)

__global__ void ms_init(const float* __restrict__ feat, const int* __restrict__ seed,
                        float* __restrict__ ws) {
    int t = blockIdx.x * blockDim.x + threadIdx.x;
    int stride = gridDim.x * blockDim.x;
    for (int i = t; i < 3 * NB * NK * NC + 3 * NB * NK; i += stride)
        ws[GNUM_OFF + i] = 0.f;
    if (t < NB * NK) {
        int b = t / NK;
        int idx = seed[t];
        float* m = ws + MEANS_OFF + NB * NK * NC + t * NC;  // means buffer 1 = means_{-1}
        for (int c = 0; c < NC; ++c)
            m[c] = feat[((size_t)b * NC + c) * NP + idx];
    }
}

// means_it = update(gnum_{it-1}, gden_{it-1}, means_{it-1}) computed per block in prologue.
// Per-k convergence: if means_it[k] == means_{it-1}[k] bitwise (it>=1), then the mask
// for k is identical -> this iteration's num/den for k are bitwise equal to the previous
// iteration's -> copy gnumR[k] -> gnumA[k] and drop k from the hot loop. Exact for any data.
__global__ __launch_bounds__(TPB, 4) void ms_accum(const float* __restrict__ feat,
                                                   float* __restrict__ ws,
                                                   int rIdx, int aIdx, int zIdx,
                                                   int prevM, int curM, int it) {
    __shared__ float sm[NK][NC];
    __shared__ float sm2[NK];
    __shared__ float snum[KPB][NC];
    __shared__ float sden[KPB];
    __shared__ unsigned char sskip[NK];
    __shared__ short act[KPB];
    __shared__ int nact;
    const int bid = blockIdx.x;
    const int ks = bid & (KS - 1);
    const int t2 = bid >> 2;
    const int b = t2 / NTILES;
    const int tile = t2 % NTILES;
    const int tid = threadIdx.x;

    float* gnumR = ws + GNUM_OFF + (size_t)rIdx * NB * NK * NC + (size_t)b * NK * NC;
    float* gnumA = ws + GNUM_OFF + (size_t)aIdx * NB * NK * NC + (size_t)b * NK * NC;
    float* gnumZ = ws + GNUM_OFF + (size_t)zIdx * NB * NK * NC + (size_t)b * NK * NC;
    float* gdenR = ws + GDEN_OFF + rIdx * NB * NK + b * NK;
    float* gdenA = ws + GDEN_OFF + aIdx * NB * NK + b * NK;
    float* gdenZ = ws + GDEN_OFF + zIdx * NB * NK + b * NK;
    float* mPrev = ws + MEANS_OFF + (size_t)prevM * NB * NK * NC + (size_t)b * NK * NC;
    float* mCur  = ws + MEANS_OFF + (size_t)curM  * NB * NK * NC + (size_t)b * NK * NC;

    // ---- prologue: every block computes all 100 new means into LDS + skip flags ----
    for (int i = tid; i < KPB * NC; i += TPB) (&snum[0][0])[i] = 0.f;
    if (tid < KPB) sden[tid] = 0.f;
    if (tid < NK) {
        const int k = tid;
        float den = gdenR[k];
        const float4* gn4 = reinterpret_cast<const float4*>(gnumR + k * NC);
        const float4* mp4 = reinterpret_cast<const float4*>(mPrev + k * NC);
        float4 g0 = gn4[0], g1 = gn4[1], g2 = gn4[2], g3 = gn4[3];
        float4 o0 = mp4[0], o1 = mp4[1], o2 = mp4[2], o3 = mp4[3];
        float gg[NC] = {g0.x,g0.y,g0.z,g0.w, g1.x,g1.y,g1.z,g1.w,
                        g2.x,g2.y,g2.z,g2.w, g3.x,g3.y,g3.z,g3.w};
        float oo[NC] = {o0.x,o0.y,o0.z,o0.w, o1.x,o1.y,o1.z,o1.w,
                        o2.x,o2.y,o2.z,o2.w, o3.x,o3.y,o3.z,o3.w};
        float inv = fmaxf(den, 1.f);
        bool pos = den > 0.f;
        float nm[NC];
        #pragma unroll
        for (int c = 0; c < NC; ++c) nm[c] = pos ? (gg[c] / inv) : oo[c];
        #pragma unroll
        for (int c = 0; c < NC; ++c) sm[k][c] = nm[c];
        float s = 0.f;
        #pragma unroll
        for (int c = 0; c < NC; ++c) s += nm[c] * nm[c];
        sm2[k] = s;
        bool same = (it >= 1);
        #pragma unroll
        for (int c = 0; c < NC; ++c)
            same = same && (__float_as_uint(nm[c]) == __float_as_uint(oo[c]));
        sskip[k] = same ? (unsigned char)1 : (unsigned char)0;
        if (ks == 0 && tile == 0) {  // persist means_it for next dispatch
            float4* mc4 = reinterpret_cast<float4*>(mCur + k * NC);
            mc4[0] = make_float4(nm[0], nm[1], nm[2], nm[3]);
            mc4[1] = make_float4(nm[4], nm[5], nm[6], nm[7]);
            mc4[2] = make_float4(nm[8], nm[9], nm[10], nm[11]);
            mc4[3] = make_float4(nm[12], nm[13], nm[14], nm[15]);
            if (same) {  // converged k: this iteration's sums == previous, copy exactly
                float4* ga4 = reinterpret_cast<float4*>(gnumA + k * NC);
                ga4[0] = g0; ga4[1] = g1; ga4[2] = g2; ga4[3] = g3;
                gdenA[k] = den;
            }
        }
    }
    // zero next iteration's global accumulation buffer (disjoint from R and A)
    if (ks == 1 && tile == 0) {
        for (int i = tid; i < NK * NC; i += TPB) gnumZ[i] = 0.f;
        if (tid < NK) gdenZ[tid] = 0.f;
    }
    __syncthreads();

    // ---- build compacted active-k list for this block's k-range ----
    const int kbeg = ks * KPB;
    if (tid == 0) {
        int n = 0;
        for (int k = kbeg; k < kbeg + KPB; ++k)
            if (!sskip[k]) act[n++] = (short)k;
        nact = n;
    }
    __syncthreads();
    if (nact == 0) return;

    // ---- load 4 points into registers (float4 per c, fully coalesced) ----
    const int p0 = tile * TILEP + tid * PT;
    float fA[NC], fB[NC], fC[NC], fD[NC];
    #pragma unroll
    for (int c = 0; c < NC; ++c) {
        float4 v = *reinterpret_cast<const float4*>(feat + ((size_t)b * NC + c) * NP + p0);
        fA[c] = v.x; fB[c] = v.y; fC[c] = v.z; fD[c] = v.w;
    }
    float f2A = 0.f, f2B = 0.f, f2C = 0.f, f2D = 0.f;
    #pragma unroll
    for (int c = 0; c < NC; ++c) f2A += fA[c] * fA[c];
    #pragma unroll
    for (int c = 0; c < NC; ++c) f2B += fB[c] * fB[c];
    #pragma unroll
    for (int c = 0; c < NC; ++c) f2C += fC[c] * fC[c];
    #pragma unroll
    for (int c = 0; c < NC; ++c) f2D += fD[c] * fD[c];

    // ---- hot loop: active k's only, broadcast LDS means, 4-way ILP FMA chains ----
    const float4* smv = reinterpret_cast<const float4*>(&sm[0][0]);
    for (int ii = 0; ii < nact; ++ii) {
        const int k = act[ii];
        float4 m0 = smv[k * 4 + 0], m1 = smv[k * 4 + 1];
        float4 m2v = smv[k * 4 + 2], m3 = smv[k * 4 + 3];
        float mm[NC] = {m0.x,m0.y,m0.z,m0.w, m1.x,m1.y,m1.z,m1.w,
                        m2v.x,m2v.y,m2v.z,m2v.w, m3.x,m3.y,m3.z,m3.w};
        float m2 = sm2[k];
        float dA = 0.f, dB = 0.f, dC = 0.f, dD = 0.f;
        #pragma unroll
        for (int c = 0; c < NC; ++c) {
            float mc = mm[c];
            dA = fmaf(fA[c], mc, dA);
            dB = fmaf(fB[c], mc, dB);
            dC = fmaf(fC[c], mc, dC);
            dD = fmaf(fD[c], mc, dD);
        }
        float d2A = (f2A - 2.f * dA) + m2;
        float d2B = (f2B - 2.f * dB) + m2;
        float d2C = (f2C - 2.f * dC) + m2;
        float d2D = (f2D - 2.f * dD) + m2;
        bool hA = d2A < BW2, hB = d2B < BW2, hC = d2C < BW2, hD = d2D < BW2;
        if (__any(hA | hB | hC | hD)) {  // rare
            int kk = k - kbeg;
            if (hA) {
                #pragma unroll
                for (int c = 0; c < NC; ++c) atomicAdd(&snum[kk][c], fA[c]);
                atomicAdd(&sden[kk], 1.f);
            }
            if (hB) {
                #pragma unroll
                for (int c = 0; c < NC; ++c) atomicAdd(&snum[kk][c], fB[c]);
                atomicAdd(&sden[kk], 1.f);
            }
            if (hC) {
                #pragma unroll
                for (int c = 0; c < NC; ++c) atomicAdd(&snum[kk][c], fC[c]);
                atomicAdd(&sden[kk], 1.f);
            }
            if (hD) {
                #pragma unroll
                for (int c = 0; c < NC; ++c) atomicAdd(&snum[kk][c], fD[c]);
                atomicAdd(&sden[kk], 1.f);
            }
        }
    }

    // ---- flush block-local sums (only nonzero entries; usually none) ----
    __syncthreads();
    for (int i = tid; i < KPB * NC; i += TPB) {
        float v = (&snum[0][0])[i];
        if (v != 0.f) atomicAdd(&gnumA[kbeg * NC + i], v);
    }
    if (tid < KPB) {
        float v = sden[tid];
        if (v != 0.f) atomicAdd(&gdenA[kbeg + tid], v);
    }
}

__global__ __launch_bounds__(TPB, 4) void ms_label(const float* __restrict__ feat,
                                                   float* __restrict__ ws,
                                                   float* __restrict__ out,
                                                   int rIdx, int prevM) {
    __shared__ float sm[NK][NC];
    __shared__ float sm2[NK];
    const int b = blockIdx.x / LNTILES;
    const int tile = blockIdx.x % LNTILES;
    const int tid = threadIdx.x;

    float* gnumR = ws + GNUM_OFF + (size_t)rIdx * NB * NK * NC + (size_t)b * NK * NC;
    float* gdenR = ws + GDEN_OFF + rIdx * NB * NK + b * NK;
    float* mPrev = ws + MEANS_OFF + (size_t)prevM * NB * NK * NC + (size_t)b * NK * NC;

    if (tid < NK) {
        const int k = tid;
        float den = gdenR[k];
        const float4* gn4 = reinterpret_cast<const float4*>(gnumR + k * NC);
        const float4* mp4 = reinterpret_cast<const float4*>(mPrev + k * NC);
        float4 g0 = gn4[0], g1 = gn4[1], g2 = gn4[2], g3 = gn4[3];
        float4 o0 = mp4[0], o1 = mp4[1], o2 = mp4[2], o3 = mp4[3];
        float gg[NC] = {g0.x,g0.y,g0.z,g0.w, g1.x,g1.y,g1.z,g1.w,
                        g2.x,g2.y,g2.z,g2.w, g3.x,g3.y,g3.z,g3.w};
        float oo[NC] = {o0.x,o0.y,o0.z,o0.w, o1.x,o1.y,o1.z,o1.w,
                        o2.x,o2.y,o2.z,o2.w, o3.x,o3.y,o3.z,o3.w};
        float inv = fmaxf(den, 1.f);
        bool pos = den > 0.f;
        float nm[NC];
        #pragma unroll
        for (int c = 0; c < NC; ++c) nm[c] = pos ? (gg[c] / inv) : oo[c];
        #pragma unroll
        for (int c = 0; c < NC; ++c) sm[k][c] = nm[c];
        float s = 0.f;
        #pragma unroll
        for (int c = 0; c < NC; ++c) s += nm[c] * nm[c];
        sm2[k] = s;
        if (tile == 0) {  // final means -> output tail
            float* mo = out + (size_t)NB * NP + (size_t)b * NK * NC + k * NC;
            float4* mo4 = reinterpret_cast<float4*>(mo);
            mo4[0] = make_float4(nm[0], nm[1], nm[2], nm[3]);
            mo4[1] = make_float4(nm[4], nm[5], nm[6], nm[7]);
            mo4[2] = make_float4(nm[8], nm[9], nm[10], nm[11]);
            mo4[3] = make_float4(nm[12], nm[13], nm[14], nm[15]);
        }
    }

    // ---- 1 point per thread, unroll-4 over k for ILP ----
    const int p = tile * LTILEP + tid;
    float fr[NC];
    #pragma unroll
    for (int c = 0; c < NC; ++c)
        fr[c] = feat[((size_t)b * NC + c) * NP + p];
    float f2 = 0.f;
    #pragma unroll
    for (int c = 0; c < NC; ++c) f2 += fr[c] * fr[c];
    __syncthreads();

    float best = 3.4e38f;
    int bi = 0;
    const float4* smv = reinterpret_cast<const float4*>(&sm[0][0]);
    #pragma unroll 4
    for (int k = 0; k < NK; ++k) {
        float4 m0 = smv[k * 4 + 0], m1 = smv[k * 4 + 1];
        float4 m2v = smv[k * 4 + 2], m3 = smv[k * 4 + 3];
        float mm[NC] = {m0.x,m0.y,m0.z,m0.w, m1.x,m1.y,m1.z,m1.w,
                        m2v.x,m2v.y,m2v.z,m2v.w, m3.x,m3.y,m3.z,m3.w};
        float m2 = sm2[k];
        float dot = 0.f;
        #pragma unroll
        for (int c = 0; c < NC; ++c) dot = fmaf(fr[c], mm[c], dot);
        float d2 = (f2 - 2.f * dot) + m2;
        if (d2 < best) { best = d2; bi = k; }
    }

    out[(size_t)b * NP + p] = (best < BW2) ? (float)(bi + 1) : 0.f;
}

extern "C" void kernel_launch(void* const* d_in, const int* in_sizes, int n_in,
                              void* d_out, int out_size, void* d_ws, size_t ws_size,
                              hipStream_t stream) {
    const float* feat = (const float*)d_in[0];
    const int* seed = (const int*)d_in[1];
    float* out = (float*)d_out;
    float* ws = (float*)d_ws;

    ms_init<<<84, 256, 0, stream>>>(feat, seed, ws);
    for (int i = 0; i < NITER; ++i) {
        ms_accum<<<NB * NTILES * KS, TPB, 0, stream>>>(
            feat, ws, (i + 2) % 3, i % 3, (i + 1) % 3, (i + 1) & 1, i & 1, i);
    }
    ms_label<<<NB * LNTILES, TPB, 0, stream>>>(feat, ws, out, (NITER + 2) % 3, (NITER + 1) & 1);
}